// Round 2
// baseline (248.616 us; speedup 1.0000x reference)
//
#include <hip/hip_runtime.h>

#define EPS 1e-8f
#define THREADS 512

typedef __attribute__((ext_vector_type(8))) short short8;
typedef __attribute__((ext_vector_type(4))) float f32x4;
typedef __attribute__((ext_vector_type(8))) unsigned short u16x8;

static __device__ __forceinline__ unsigned short f2bf(float f) {
  unsigned int u = __float_as_uint(f);
  u += 0x7FFF + ((u >> 16) & 1);   // round-to-nearest-even
  return (unsigned short)(u >> 16);
}

// ---------- K1 fused: blocks 0..15 -> style matmul; blocks 16..271 -> weight prep ----------
// style: s[b,ci] = style[b,:] @ mod_weight[ci,:] + mod_bias[ci]
// wprep: wsq[co,ci] = sum_r W^2 ; wbf = bf16 W pre-swizzled panels
//        panel (c,r): 256 co x 64 ci, byte = (co*128 + cil*2) ^ ((co&7)<<4)
__global__ void k_prep(const float* __restrict__ style, const float* __restrict__ mw,
                       const float* __restrict__ mb, float* __restrict__ s_out,
                       const float* __restrict__ weight, float* __restrict__ wsq,
                       unsigned short* __restrict__ wbf) {
  __shared__ float sm[2304];
  int t = threadIdx.x;
  if (blockIdx.x < 16) {
    int b = blockIdx.x;
    sm[t]       = style[b*512 + t];
    sm[t + 256] = style[b*512 + 256 + t];
    __syncthreads();
    const float4* row = (const float4*)(mw + (size_t)t*512);
    float acc = 0.f;
#pragma unroll 4
    for (int i = 0; i < 128; ++i) {
      float4 m = row[i];
      acc += m.x*sm[4*i] + m.y*sm[4*i+1] + m.z*sm[4*i+2] + m.w*sm[4*i+3];
    }
    s_out[b*256 + t] = acc + mb[t];
  } else {
    int co = blockIdx.x - 16;
    // coalesced stage of this co's 256x9 weights
    for (int q = t; q < 576; q += 256)
      *(float4*)&sm[q*4] = *(const float4*)(weight + (size_t)co*2304 + q*4);
    __syncthreads();
    int ci = t;
    int c = ci >> 6, cil = ci & 63;
    int base = ((co*128 + cil*2) ^ ((co & 7) << 4)) >> 1;
    float sum = 0.f;
#pragma unroll
    for (int r = 0; r < 9; ++r) {
      float v = sm[ci*9 + r];
      sum += v*v;
      wbf[(size_t)(c*9 + r)*16384 + base] = f2bf(v);
    }
    wsq[co*256 + ci] = sum;
  }
}

// ---------- K2: demod[b,co] = rsqrt(sum_ci wsq[co,ci]*s[b,ci]^2 + eps) ----------
__global__ void k_demod(const float* __restrict__ s, const float* __restrict__ wsq,
                        float* __restrict__ dm) {
  int b = blockIdx.x, t = threadIdx.x;
  __shared__ float s2[256];
  float sv = s[b*256 + t];
  s2[t] = sv*sv;
  __syncthreads();
  const float4* row = (const float4*)(wsq + (size_t)t*256);
  float acc = 0.f;
#pragma unroll 4
  for (int i = 0; i < 64; ++i) {
    float4 q = row[i];
    acc += q.x*s2[4*i] + q.y*s2[4*i+1] + q.z*s2[4*i+2] + q.w*s2[4*i+3];
  }
  dm[b*256 + t] = rsqrtf(acc + EPS);
}

// ---------- K3: xp[b][gh][gw][ci] = bf16( x[b][ci][gh-1][gw-1] * s[b][ci] ), zero-padded ----------
__global__ void k_pad(const float* __restrict__ x, const float* __restrict__ s,
                      unsigned short* __restrict__ xp) {
  int bid = blockIdx.x;
  int b = bid / 66, gh = bid - b*66;
  int t = threadIdx.x;
  size_t rowbase = (size_t)(b*66 + gh) * (66*256);
  u16x8* rp = (u16x8*)(xp + rowbase);
  if (gh == 0 || gh == 65) {
    u16x8 z = (u16x8)0;
    for (int q = t; q < 2112; q += 256) rp[q] = z;
    return;
  }
  int h = gh - 1;
  __shared__ float sl[256];
  __shared__ unsigned short xl[64*256];   // [w][ci], 16B-slot swizzled: byte = w*512 + ((oct^(w&31))<<4) + (ci&7)*2
  sl[t] = s[b*256 + t];
  __syncthreads();
  int w4 = (t & 15) * 4, o0 = t >> 4;
#pragma unroll
  for (int p = 0; p < 2; ++p) {
    int oct = o0 + p*16;
    u16x8 outv[4];
#pragma unroll
    for (int j = 0; j < 8; ++j) {
      int ci = oct*8 + j;
      float4 v = *(const float4*)(x + ((size_t)(b*256 + ci)*64 + h)*64 + w4);
      float sc = sl[ci];
      outv[0][j] = (short)f2bf(v.x * sc);
      outv[1][j] = (short)f2bf(v.y * sc);
      outv[2][j] = (short)f2bf(v.z * sc);
      outv[3][j] = (short)f2bf(v.w * sc);
    }
#pragma unroll
    for (int k = 0; k < 4; ++k) {
      int w = w4 + k;
      int byte = w*512 + ((oct ^ (w & 31)) << 4);
      *(u16x8*)((char*)xl + byte) = outv[k];
    }
  }
  __syncthreads();
  u16x8 z = (u16x8)0;
  if (t < 32) rp[t] = z;                       // gw = 0 pad column
  else if (t < 64) rp[65*32 + (t - 32)] = z;   // gw = 65 pad column
  for (int q = t; q < 2048; q += 256) {
    int w2 = q >> 5, slot = q & 31;
    u16x8 v = *(const u16x8*)((char*)xl + w2*512 + ((slot ^ (w2 & 31)) << 4));
    rp[(w2 + 1)*32 + slot] = v;               // xp global layout is LINEAR [gw][ci]
  }
}

// ---------- K4: conv as implicit GEMM ----------
// grid 512 = 16 b x 32 h-tiles (XCD-swizzled); block = 256co x (2h x 64w), 8 waves.
// wave (wm = wave>>1, wn = wave&1): 64 co x 64 n (one output row).
// LDS 66560 B -> 2 blocks/CU.
__global__ __launch_bounds__(512, 4)
void k_conv(const unsigned short* __restrict__ xp, const unsigned short* __restrict__ wbf,
            const float* __restrict__ dm, const float* __restrict__ bias,
            float* __restrict__ out) {
  __shared__ unsigned short x_lds[4*66*64];   // 33792 B, row = hl*66+gw, 64 ci, XOR-swizzled
  __shared__ unsigned short w_lds[256*64];    // 32768 B, row = co, 64 ci, XOR-swizzled

  const int tid = threadIdx.x;
  const int lane = tid & 63;
  const int wave = tid >> 6;
  const int bid = (blockIdx.x & 7)*64 + (blockIdx.x >> 3);   // XCD-bijective (512 % 8 == 0)
  const int b = bid >> 5;
  const int h0 = (bid & 31) * 2;
  const int wm = wave >> 1, wn = wave & 1;
  const int l15 = lane & 15, lk = lane >> 4;

  f32x4 acc[4][4];
#pragma unroll
  for (int m = 0; m < 4; ++m)
#pragma unroll
    for (int f = 0; f < 4; ++f) acc[m][f] = (f32x4)0.f;

  for (int c = 0; c < 4; ++c) {
    __syncthreads();   // previous chunk's x_lds reads complete
    {
      // stage x tile: 4 rows x 66 gw x 64 ci bf16 = 2112 16B chunks
      int cb = c*64;
#pragma unroll
      for (int it = 0; it < 5; ++it) {
        int q = it*THREADS + tid;
        if (q < 2112) {
          int hw = q >> 3;
          int hl = hw / 66, w = hw - hl*66;
          int slot = (q & 7) ^ (hw & 7);
          const unsigned short* src =
              xp + (size_t)((b*66 + h0 + hl)*66 + w)*256 + cb + slot*8;
          __builtin_amdgcn_global_load_lds(
              (const __attribute__((address_space(1))) void*)src,
              (__attribute__((address_space(3))) void*)&x_lds[(size_t)q*8],
              16, 0, 0);
        }
      }
    }
    for (int r = 0; r < 9; ++r) {
      if (r) __syncthreads();   // previous r's w_lds reads complete
      {
        const unsigned short* wsrc = wbf + (size_t)(c*9 + r)*16384;  // pre-swizzled, linear copy
#pragma unroll
        for (int it = 0; it < 4; ++it) {
          int q = it*THREADS + tid;
          __builtin_amdgcn_global_load_lds(
              (const __attribute__((address_space(1))) void*)(wsrc + (size_t)q*8),
              (__attribute__((address_space(3))) void*)&w_lds[(size_t)q*8],
              16, 0, 0);
        }
      }
      __syncthreads();   // drains vmcnt: staged x & w visible
      int dh = r / 3, dw = r - dh*3;
#pragma unroll
      for (int kh = 0; kh < 2; ++kh) {
        int cio = (kh*32 + lk*8)*2;   // byte offset of this lane's k-slice
        short8 a[4], bf[4];
#pragma unroll
        for (int m = 0; m < 4; ++m) {
          int co = wm*64 + m*16 + l15;
          int byte = (co*128 + cio) ^ ((co & 7) << 4);
          a[m] = *(const short8*)((const char*)w_lds + byte);
        }
#pragma unroll
        for (int f = 0; f < 4; ++f) {
          int row = (wn + dh)*66 + (f*16 + l15 + dw);
          int byte = (row*128 + cio) ^ ((row & 7) << 4);
          bf[f] = *(const short8*)((const char*)x_lds + byte);
        }
#pragma unroll
        for (int m = 0; m < 4; ++m)
#pragma unroll
          for (int f = 0; f < 4; ++f)
            acc[m][f] = __builtin_amdgcn_mfma_f32_16x16x32_bf16(a[m], bf[f], acc[m][f], 0, 0, 0);
      }
    }
  }

  // epilogue: D col = lane&15 (w), row = (lane>>4)*4 + j (co offset)
  int colane = (lane >> 4) * 4;
#pragma unroll
  for (int m = 0; m < 4; ++m) {
    int cob = wm*64 + m*16 + colane;
    float4 d4 = *(const float4*)&dm[b*256 + cob];
    float4 b4 = *(const float4*)&bias[cob];
    int h = h0 + wn;
#pragma unroll
    for (int f = 0; f < 4; ++f) {
      int wc = f*16 + l15;
      float* op = out + ((size_t)(b*256 + cob)*64 + h)*64 + wc;
      op[0]     = acc[m][f][0] * d4.x + b4.x;
      op[4096]  = acc[m][f][1] * d4.y + b4.y;
      op[8192]  = acc[m][f][2] * d4.z + b4.z;
      op[12288] = acc[m][f][3] * d4.w + b4.w;
    }
  }
}

extern "C" void kernel_launch(void* const* d_in, const int* in_sizes, int n_in,
                              void* d_out, int out_size, void* d_ws, size_t ws_size,
                              hipStream_t stream) {
  const float* x      = (const float*)d_in[0];
  const float* style  = (const float*)d_in[1];
  const float* mw     = (const float*)d_in[2];
  const float* mb     = (const float*)d_in[3];
  const float* weight = (const float*)d_in[4];
  const float* bias   = (const float*)d_in[5];
  float* out = (float*)d_out;

  char* ws = (char*)d_ws;
  float* s_buf        = (float*)(ws);                             // 16 KB
  float* wsq          = (float*)(ws + 16384);                     // 256 KB
  float* dmod         = (float*)(ws + 16384 + 262144);            // 16 KB
  unsigned short* wbf = (unsigned short*)(ws + 294912);           // 1.125 MB
  unsigned short* xpd = (unsigned short*)(ws + 294912 + 1179648); // 34.03 MB

  k_prep<<<272, 256, 0, stream>>>(style, mw, mb, s_buf, weight, wsq, wbf);
  k_demod<<<16, 256, 0, stream>>>(s_buf, wsq, dmod);
  k_pad<<<16*66, 256, 0, stream>>>(x, s_buf, xpd);
  k_conv<<<512, 512, 0, stream>>>(xpd, wbf, dmod, bias, out);
}

// Round 3
// 224.319 us; speedup vs baseline: 1.1083x; 1.1083x over previous
//
#include <hip/hip_runtime.h>

#define EPS 1e-8f
#define THREADS 512

typedef __attribute__((ext_vector_type(8))) short short8;
typedef __attribute__((ext_vector_type(4))) float f32x4;
typedef __attribute__((ext_vector_type(8))) unsigned short u16x8;

static __device__ __forceinline__ unsigned short f2bf(float f) {
  unsigned int u = __float_as_uint(f);
  u += 0x7FFF + ((u >> 16) & 1);   // round-to-nearest-even
  return (unsigned short)(u >> 16);
}

// ---------- K1 fused: blocks 0..15 -> style matmul; blocks 16..271 -> weight prep ----------
__global__ void k_prep(const float* __restrict__ style, const float* __restrict__ mw,
                       const float* __restrict__ mb, float* __restrict__ s_out,
                       const float* __restrict__ weight, float* __restrict__ wsq,
                       unsigned short* __restrict__ wbf) {
  __shared__ float sm[2304];
  int t = threadIdx.x;
  if (blockIdx.x < 16) {
    int b = blockIdx.x;
    sm[t]       = style[b*512 + t];
    sm[t + 256] = style[b*512 + 256 + t];
    __syncthreads();
    const float4* row = (const float4*)(mw + (size_t)t*512);
    float acc = 0.f;
#pragma unroll 4
    for (int i = 0; i < 128; ++i) {
      float4 m = row[i];
      acc += m.x*sm[4*i] + m.y*sm[4*i+1] + m.z*sm[4*i+2] + m.w*sm[4*i+3];
    }
    s_out[b*256 + t] = acc + mb[t];
  } else {
    int co = blockIdx.x - 16;
    for (int q = t; q < 576; q += 256)
      *(float4*)&sm[q*4] = *(const float4*)(weight + (size_t)co*2304 + q*4);
    __syncthreads();
    int ci = t;
    int c = ci >> 6, cil = ci & 63;
    int base = ((co*128 + cil*2) ^ ((co & 7) << 4)) >> 1;
    float sum = 0.f;
#pragma unroll
    for (int r = 0; r < 9; ++r) {
      float v = sm[ci*9 + r];
      sum += v*v;
      wbf[(size_t)(c*9 + r)*16384 + base] = f2bf(v);
    }
    wsq[co*256 + ci] = sum;
  }
}

// ---------- K2: demod[b,co] = rsqrt(sum_ci wsq[co,ci]*s[b,ci]^2 + eps) ----------
__global__ void k_demod(const float* __restrict__ s, const float* __restrict__ wsq,
                        float* __restrict__ dm) {
  int b = blockIdx.x, t = threadIdx.x;
  __shared__ float s2[256];
  float sv = s[b*256 + t];
  s2[t] = sv*sv;
  __syncthreads();
  const float4* row = (const float4*)(wsq + (size_t)t*256);
  float acc = 0.f;
#pragma unroll 4
  for (int i = 0; i < 64; ++i) {
    float4 q = row[i];
    acc += q.x*s2[4*i] + q.y*s2[4*i+1] + q.z*s2[4*i+2] + q.w*s2[4*i+3];
  }
  dm[b*256 + t] = rsqrtf(acc + EPS);
}

// ---------- K3: xp[b][gh][gw][ci] = bf16( x[b][ci][gh-1][gw-1] * s[b][ci] ), zero-padded ----------
__global__ void k_pad(const float* __restrict__ x, const float* __restrict__ s,
                      unsigned short* __restrict__ xp) {
  int bid = blockIdx.x;
  int b = bid / 66, gh = bid - b*66;
  int t = threadIdx.x;
  size_t rowbase = (size_t)(b*66 + gh) * (66*256);
  u16x8* rp = (u16x8*)(xp + rowbase);
  if (gh == 0 || gh == 65) {
    u16x8 z = (u16x8)0;
    for (int q = t; q < 2112; q += 256) rp[q] = z;
    return;
  }
  int h = gh - 1;
  __shared__ float sl[256];
  __shared__ unsigned short xl[64*256];   // [w][ci], 16B-slot swizzled
  sl[t] = s[b*256 + t];
  __syncthreads();
  int w4 = (t & 15) * 4, o0 = t >> 4;
#pragma unroll
  for (int p = 0; p < 2; ++p) {
    int oct = o0 + p*16;
    u16x8 outv[4];
#pragma unroll
    for (int j = 0; j < 8; ++j) {
      int ci = oct*8 + j;
      float4 v = *(const float4*)(x + ((size_t)(b*256 + ci)*64 + h)*64 + w4);
      float sc = sl[ci];
      outv[0][j] = (short)f2bf(v.x * sc);
      outv[1][j] = (short)f2bf(v.y * sc);
      outv[2][j] = (short)f2bf(v.z * sc);
      outv[3][j] = (short)f2bf(v.w * sc);
    }
#pragma unroll
    for (int k = 0; k < 4; ++k) {
      int w = w4 + k;
      int byte = w*512 + ((oct ^ (w & 31)) << 4);
      *(u16x8*)((char*)xl + byte) = outv[k];
    }
  }
  __syncthreads();
  u16x8 z = (u16x8)0;
  if (t < 32) rp[t] = z;
  else if (t < 64) rp[65*32 + (t - 32)] = z;
  for (int q = t; q < 2048; q += 256) {
    int w2 = q >> 5, slot = q & 31;
    u16x8 v = *(const u16x8*)((char*)xl + w2*512 + ((slot ^ (w2 & 31)) << 4));
    rp[(w2 + 1)*32 + slot] = v;
  }
}

// ---------- K4: conv as implicit GEMM, w-panel software pipeline ----------
// grid 256 = 16 b x 16 h-tiles; block = 256co x (4h x 64w), 8 waves (4 wm x 2 wn).
// x_lds single-buffered per ci-chunk; w_lds double-buffered, prefetched one phase ahead.
__global__ __launch_bounds__(512, 2)
void k_conv(const unsigned short* __restrict__ xp, const unsigned short* __restrict__ wbf,
            const float* __restrict__ dm, const float* __restrict__ bias,
            float* __restrict__ out) {
  __shared__ unsigned short x_lds[6*66*64];      // 50688 B, row = hl*66+gw, XOR-swizzled
  __shared__ unsigned short w_lds[2][256*64];    // 2 x 32768 B, row = co, XOR-swizzled

  const int tid = threadIdx.x;
  const int lane = tid & 63;
  const int wave = tid >> 6;
  const int b = blockIdx.x >> 4;
  const int h0 = (blockIdx.x & 15) * 4;
  const int wm = wave >> 1, wn = wave & 1;
  const int l15 = lane & 15, lk = lane >> 4;

  f32x4 acc[4][8];
#pragma unroll
  for (int m = 0; m < 4; ++m)
#pragma unroll
    for (int f = 0; f < 8; ++f) acc[m][f] = (f32x4)0.f;

  // ---- staging helpers (inlined lambdas) ----
  auto stage_x = [&](int c) {
    int cb = c*64;
#pragma unroll
    for (int it = 0; it < 7; ++it) {
      int q = it*THREADS + tid;
      if (q < 3168) {
        int hw = q >> 3;
        int hl = hw / 66, w = hw - hl*66;
        int slot = (q & 7) ^ (hw & 7);
        const unsigned short* src =
            xp + (size_t)((b*66 + h0 + hl)*66 + w)*256 + cb + slot*8;
        __builtin_amdgcn_global_load_lds(
            (const __attribute__((address_space(1))) void*)src,
            (__attribute__((address_space(3))) void*)&x_lds[(size_t)q*8],
            16, 0, 0);
      }
    }
  };
  auto stage_w = [&](int p, int buf) {
    const unsigned short* wsrc = wbf + (size_t)p*16384;   // pre-swizzled, linear copy
#pragma unroll
    for (int it = 0; it < 4; ++it) {
      int q = it*THREADS + tid;
      __builtin_amdgcn_global_load_lds(
          (const __attribute__((address_space(1))) void*)(wsrc + (size_t)q*8),
          (__attribute__((address_space(3))) void*)&w_lds[buf][(size_t)q*8],
          16, 0, 0);
    }
  };

  // ---- prologue ----
  stage_x(0);
  stage_w(0, 0);
  __syncthreads();   // implicit vmcnt(0): x(0) + w(0) landed

  for (int c = 0; c < 4; ++c) {
    for (int r = 0; r < 9; ++r) {
      int p = c*9 + r;
      if (p < 35) stage_w(p + 1, (p + 1) & 1);   // prefetch next panel (hidden under MFMA)
      const unsigned short* wb = w_lds[p & 1];
      int dh = r / 3, dw = r - dh*3;
#pragma unroll
      for (int kh = 0; kh < 2; ++kh) {
        int cio = kh*64 + lk*16;    // byte offset of this lane's 16B k-slice
        short8 a[4], bf[8];
#pragma unroll
        for (int m = 0; m < 4; ++m) {
          int co = wm*64 + m*16 + l15;
          int byte = (co*128 + cio) ^ ((co & 7) << 4);
          a[m] = *(const short8*)((const char*)wb + byte);
        }
#pragma unroll
        for (int f = 0; f < 8; ++f) {
          int row = (wn*2 + (f >> 2) + dh)*66 + ((f & 3)*16 + l15 + dw);
          int byte = (row*128 + cio) ^ ((row & 7) << 4);
          bf[f] = *(const short8*)((const char*)x_lds + byte);
        }
        __builtin_amdgcn_s_setprio(1);
#pragma unroll
        for (int m = 0; m < 4; ++m)
#pragma unroll
          for (int f = 0; f < 8; ++f)
            acc[m][f] = __builtin_amdgcn_mfma_f32_16x16x32_bf16(a[m], bf[f], acc[m][f], 0, 0, 0);
        __builtin_amdgcn_s_setprio(0);
      }
      if (r == 8) {
        __syncthreads();                 // all waves done reading x_lds
        if (c < 3) stage_x(c + 1);
        __syncthreads();                 // drain x (and w) loads
      } else {
        __syncthreads();                 // drain w(p+1); release wbuf[(p+1)&1] readers
      }
    }
  }

  // ---- epilogue: D col = lane&15 (w), row = (lane>>4)*4 + j (co offset) ----
  int colane = (lane >> 4) * 4;
#pragma unroll
  for (int m = 0; m < 4; ++m) {
    int cob = wm*64 + m*16 + colane;
    float4 d4 = *(const float4*)&dm[b*256 + cob];
    float4 b4 = *(const float4*)&bias[cob];
#pragma unroll
    for (int f = 0; f < 8; ++f) {
      int h = h0 + wn*2 + (f >> 2);
      int wc = (f & 3)*16 + l15;
      float* op = out + ((size_t)(b*256 + cob)*64 + h)*64 + wc;
      op[0]     = acc[m][f][0] * d4.x + b4.x;
      op[4096]  = acc[m][f][1] * d4.y + b4.y;
      op[8192]  = acc[m][f][2] * d4.z + b4.z;
      op[12288] = acc[m][f][3] * d4.w + b4.w;
    }
  }
}

extern "C" void kernel_launch(void* const* d_in, const int* in_sizes, int n_in,
                              void* d_out, int out_size, void* d_ws, size_t ws_size,
                              hipStream_t stream) {
  const float* x      = (const float*)d_in[0];
  const float* style  = (const float*)d_in[1];
  const float* mw     = (const float*)d_in[2];
  const float* mb     = (const float*)d_in[3];
  const float* weight = (const float*)d_in[4];
  const float* bias   = (const float*)d_in[5];
  float* out = (float*)d_out;

  char* ws = (char*)d_ws;
  float* s_buf        = (float*)(ws);                             // 16 KB
  float* wsq          = (float*)(ws + 16384);                     // 256 KB
  float* dmod         = (float*)(ws + 16384 + 262144);            // 16 KB
  unsigned short* wbf = (unsigned short*)(ws + 294912);           // 1.125 MB
  unsigned short* xpd = (unsigned short*)(ws + 294912 + 1179648); // 34.03 MB

  k_prep<<<272, 256, 0, stream>>>(style, mw, mb, s_buf, weight, wsq, wbf);
  k_demod<<<16, 256, 0, stream>>>(s_buf, wsq, dmod);
  k_pad<<<16*66, 256, 0, stream>>>(x, s_buf, xpd);
  k_conv<<<256, 512, 0, stream>>>(xpd, wbf, dmod, bias, out);
}

// Round 4
// 218.042 us; speedup vs baseline: 1.1402x; 1.0288x over previous
//
#include <hip/hip_runtime.h>

#define EPS 1e-8f
#define THREADS 512

typedef __attribute__((ext_vector_type(8))) short short8;
typedef __attribute__((ext_vector_type(4))) float f32x4;
typedef __attribute__((ext_vector_type(8))) unsigned short u16x8;

static __device__ __forceinline__ unsigned short f2bf(float f) {
  unsigned int u = __float_as_uint(f);
  u += 0x7FFF + ((u >> 16) & 1);   // round-to-nearest-even
  return (unsigned short)(u >> 16);
}

// ---------- K1 fused: blocks 0..15 -> style matmul; blocks 16..271 -> weight prep ----------
__global__ void k_prep(const float* __restrict__ style, const float* __restrict__ mw,
                       const float* __restrict__ mb, float* __restrict__ s_out,
                       const float* __restrict__ weight, float* __restrict__ wsq,
                       unsigned short* __restrict__ wbf) {
  __shared__ float sm[2304];
  int t = threadIdx.x;
  if (blockIdx.x < 16) {
    int b = blockIdx.x;
    sm[t]       = style[b*512 + t];
    sm[t + 256] = style[b*512 + 256 + t];
    __syncthreads();
    const float4* row = (const float4*)(mw + (size_t)t*512);
    float acc = 0.f;
#pragma unroll 4
    for (int i = 0; i < 128; ++i) {
      float4 m = row[i];
      acc += m.x*sm[4*i] + m.y*sm[4*i+1] + m.z*sm[4*i+2] + m.w*sm[4*i+3];
    }
    s_out[b*256 + t] = acc + mb[t];
  } else {
    int co = blockIdx.x - 16;
    for (int q = t; q < 576; q += 256)
      *(float4*)&sm[q*4] = *(const float4*)(weight + (size_t)co*2304 + q*4);
    __syncthreads();
    int ci = t;
    int c = ci >> 6, cil = ci & 63;
    int base = ((co*128 + cil*2) ^ ((co & 7) << 4)) >> 1;
    float sum = 0.f;
#pragma unroll
    for (int r = 0; r < 9; ++r) {
      float v = sm[ci*9 + r];
      sum += v*v;
      wbf[(size_t)(c*9 + r)*16384 + base] = f2bf(v);
    }
    wsq[co*256 + ci] = sum;
  }
}

// ---------- K3: xp[b][gh][gw][ci] = bf16( x[b][ci][gh-1][gw-1] * s[b][ci] ), zero-padded ----------
__global__ void k_pad(const float* __restrict__ x, const float* __restrict__ s,
                      unsigned short* __restrict__ xp) {
  int bid = blockIdx.x;
  int b = bid / 66, gh = bid - b*66;
  int t = threadIdx.x;
  size_t rowbase = (size_t)(b*66 + gh) * (66*256);
  u16x8* rp = (u16x8*)(xp + rowbase);
  if (gh == 0 || gh == 65) {
    u16x8 z = (u16x8)0;
    for (int q = t; q < 2112; q += 256) rp[q] = z;
    return;
  }
  int h = gh - 1;
  __shared__ float sl[256];
  __shared__ unsigned short xl[64*256];   // [w][ci], 16B-slot swizzled
  sl[t] = s[b*256 + t];
  __syncthreads();
  int w4 = (t & 15) * 4, o0 = t >> 4;
#pragma unroll
  for (int p = 0; p < 2; ++p) {
    int oct = o0 + p*16;
    u16x8 outv[4];
#pragma unroll
    for (int j = 0; j < 8; ++j) {
      int ci = oct*8 + j;
      float4 v = *(const float4*)(x + ((size_t)(b*256 + ci)*64 + h)*64 + w4);
      float sc = sl[ci];
      outv[0][j] = (short)f2bf(v.x * sc);
      outv[1][j] = (short)f2bf(v.y * sc);
      outv[2][j] = (short)f2bf(v.z * sc);
      outv[3][j] = (short)f2bf(v.w * sc);
    }
#pragma unroll
    for (int k = 0; k < 4; ++k) {
      int w = w4 + k;
      int byte = w*512 + ((oct ^ (w & 31)) << 4);
      *(u16x8*)((char*)xl + byte) = outv[k];
    }
  }
  __syncthreads();
  u16x8 z = (u16x8)0;
  if (t < 32) rp[t] = z;
  else if (t < 64) rp[65*32 + (t - 32)] = z;
  for (int q = t; q < 2048; q += 256) {
    int w2 = q >> 5, slot = q & 31;
    u16x8 v = *(const u16x8*)((char*)xl + w2*512 + ((slot ^ (w2 & 31)) << 4));
    rp[(w2 + 1)*32 + slot] = v;
  }
}

// ---------- K4: conv as implicit GEMM, counted-vmcnt pipeline + fused demod ----------
// grid 256 = 16 b x 16 h-tiles; block = 256co x (4h x 64w), 8 waves (4 wm x 2 wn).
// Per phase p: issue stage_w(p+1) -> s_waitcnt vmcnt(4) -> s_barrier -> ds_read+MFMA
// -> s_barrier. The 4 p+1 loads stay in flight across barriers (T3/T4).
__global__ __launch_bounds__(512, 2)
void k_conv(const unsigned short* __restrict__ xp, const unsigned short* __restrict__ wbf,
            const float* __restrict__ s_buf, const float* __restrict__ wsq,
            const float* __restrict__ bias, float* __restrict__ out) {
  __shared__ unsigned short x_lds[3168*8];     // 50688 B, row = hl*66+gw, XOR-swizzled
  __shared__ unsigned short w_lds[2*16384];    // 2 x 32768 B, row = co, XOR-swizzled
  __shared__ float s2s[256];
  __shared__ float dms[256];

  const int tid = threadIdx.x;
  const int lane = tid & 63;
  const int wave = tid >> 6;
  const int b = blockIdx.x >> 4;
  const int h0 = (blockIdx.x & 15) * 4;
  const int wm = wave >> 1, wn = wave & 1;
  const int l15 = lane & 15, lk = lane >> 4;

  auto stage_x = [&](int c) {
    int cb = c*64;
#pragma unroll
    for (int it = 0; it < 7; ++it) {
      int q = it*THREADS + tid;
      if (q < 3168) {
        int hw = q >> 3;
        int hl = hw / 66, w = hw - hl*66;
        int slot = (q & 7) ^ (hw & 7);
        const unsigned short* src =
            xp + (size_t)((b*66 + h0 + hl)*66 + w)*256 + cb + slot*8;
        __builtin_amdgcn_global_load_lds(
            (const __attribute__((address_space(1))) void*)src,
            (__attribute__((address_space(3))) void*)&x_lds[(size_t)q*8],
            16, 0, 0);
      }
    }
  };
  auto stage_w = [&](int p) {
    const unsigned short* wsrc = wbf + (size_t)p*16384;   // pre-swizzled, linear copy
    unsigned short* dst = &w_lds[(p & 1)*16384];
#pragma unroll
    for (int it = 0; it < 4; ++it) {
      int q = it*THREADS + tid;
      __builtin_amdgcn_global_load_lds(
          (const __attribute__((address_space(1))) void*)(wsrc + (size_t)q*8),
          (__attribute__((address_space(3))) void*)&dst[(size_t)q*8],
          16, 0, 0);
    }
  };

  // ---- prologue: start staging immediately, compute demod under the loads ----
  stage_x(0);
  stage_w(0);

  if (tid < 256) { float sv = s_buf[b*256 + tid]; s2s[tid] = sv*sv; }
  asm volatile("s_waitcnt lgkmcnt(0)" ::: "memory");
  __builtin_amdgcn_s_barrier();
  {
    int co = tid >> 1, half = tid & 1;
    const float4* row = (const float4*)(wsq + (size_t)co*256 + half*128);
    const float* sp = &s2s[half*128];
    float a = 0.f;
#pragma unroll 4
    for (int i = 0; i < 32; ++i) {
      float4 q = row[i];
      a += q.x*sp[4*i] + q.y*sp[4*i+1] + q.z*sp[4*i+2] + q.w*sp[4*i+3];
    }
    a += __shfl_xor(a, 1);
    if (half == 0) dms[co] = rsqrtf(a + EPS);
  }

  f32x4 acc[4][8];
#pragma unroll
  for (int m = 0; m < 4; ++m)
#pragma unroll
    for (int f = 0; f < 8; ++f) acc[m][f] = (f32x4)0.f;

  asm volatile("s_waitcnt vmcnt(0) lgkmcnt(0)" ::: "memory");
  __builtin_amdgcn_s_barrier();      // x(0), w(0), dms all visible

  for (int c = 0; c < 4; ++c) {
    for (int r = 0; r < 9; ++r) {
      int p = c*9 + r;
      if (r == 0 && c > 0) stage_x(c);          // x_lds released by prev end-barrier
      if (p < 35) {
        stage_w(p + 1);                         // into buf (p+1)&1, released by prev end-barrier
        asm volatile("s_waitcnt vmcnt(4)" ::: "memory");   // drain w(p) + x; keep w(p+1) in flight
      } else {
        asm volatile("s_waitcnt vmcnt(0)" ::: "memory");
      }
      __builtin_amdgcn_s_barrier();             // all waves' data landed
      __builtin_amdgcn_sched_barrier(0);

      const unsigned short* wbp = &w_lds[(p & 1)*16384];
      int dh = r / 3, dw = r - dh*3;
#pragma unroll
      for (int kh = 0; kh < 2; ++kh) {
        int cio = kh*64 + lk*16;    // byte offset of this lane's 16B k-slice
        short8 a[4], bv[8];
#pragma unroll
        for (int m = 0; m < 4; ++m) {
          int co = wm*64 + m*16 + l15;
          int byte = (co*128 + cio) ^ ((co & 7) << 4);
          a[m] = *(const short8*)((const char*)wbp + byte);
        }
#pragma unroll
        for (int f = 0; f < 8; ++f) {
          int row = (wn*2 + (f >> 2) + dh)*66 + ((f & 3)*16 + l15 + dw);
          int byte = (row*128 + cio) ^ ((row & 7) << 4);
          bv[f] = *(const short8*)((const char*)x_lds + byte);
        }
        __builtin_amdgcn_s_setprio(1);
#pragma unroll
        for (int m = 0; m < 4; ++m)
#pragma unroll
          for (int f = 0; f < 8; ++f)
            acc[m][f] = __builtin_amdgcn_mfma_f32_16x16x32_bf16(a[m], bv[f], acc[m][f], 0, 0, 0);
        __builtin_amdgcn_s_setprio(0);
      }
      __builtin_amdgcn_sched_barrier(0);
      __builtin_amdgcn_s_barrier();             // read-release: w-buf (p+2)&1 / x_lds reusable
    }
  }

  // ---- epilogue: D col = lane&15 (w), row = (lane>>4)*4 + j (co offset) ----
  int colane = (lane >> 4) * 4;
#pragma unroll
  for (int m = 0; m < 4; ++m) {
    int cob = wm*64 + m*16 + colane;
    float4 d4 = *(const float4*)&dms[cob];
    float4 b4 = *(const float4*)&bias[cob];
#pragma unroll
    for (int f = 0; f < 8; ++f) {
      int h = h0 + wn*2 + (f >> 2);
      int wc = (f & 3)*16 + l15;
      float* op = out + ((size_t)(b*256 + cob)*64 + h)*64 + wc;
      op[0]     = acc[m][f][0] * d4.x + b4.x;
      op[4096]  = acc[m][f][1] * d4.y + b4.y;
      op[8192]  = acc[m][f][2] * d4.z + b4.z;
      op[12288] = acc[m][f][3] * d4.w + b4.w;
    }
  }
}

extern "C" void kernel_launch(void* const* d_in, const int* in_sizes, int n_in,
                              void* d_out, int out_size, void* d_ws, size_t ws_size,
                              hipStream_t stream) {
  const float* x      = (const float*)d_in[0];
  const float* style  = (const float*)d_in[1];
  const float* mw     = (const float*)d_in[2];
  const float* mb     = (const float*)d_in[3];
  const float* weight = (const float*)d_in[4];
  const float* bias   = (const float*)d_in[5];
  float* out = (float*)d_out;

  char* ws = (char*)d_ws;
  float* s_buf        = (float*)(ws);                             // 16 KB
  float* wsq          = (float*)(ws + 16384);                     // 256 KB
  unsigned short* wbf = (unsigned short*)(ws + 294912);           // 1.125 MB
  unsigned short* xpd = (unsigned short*)(ws + 294912 + 1179648); // 34.03 MB

  k_prep<<<272, 256, 0, stream>>>(style, mw, mb, s_buf, weight, wsq, wbf);
  k_pad<<<16*66, 256, 0, stream>>>(x, s_buf, xpd);
  k_conv<<<256, 512, 0, stream>>>(xpd, wbf, s_buf, wsq, bias, out);
}